// Round 5
// baseline (1595.948 us; speedup 1.0000x reference)
//
#include <hip/hip_runtime.h>

typedef __attribute__((ext_vector_type(8))) _Float16 half8;
typedef __attribute__((ext_vector_type(4))) _Float16 half4;
typedef __attribute__((ext_vector_type(4))) float f32x4;

#define BN_EPS 1e-5f

__device__ __forceinline__ void async_copy16(const void* g, void* l) {
  __builtin_amdgcn_global_load_lds((const __attribute__((address_space(1))) void*)g,
                                   (__attribute__((address_space(3))) void*)l,
                                   16, 0, 0);
}

// ---------------- kernel 1: x (B,C,N) fp32 -> xT (B,N,C) fp16 ----------------
__global__ void k_transpose(const float* __restrict__ x, _Float16* __restrict__ xT) {
  __shared__ float tile[64][65];
  int n0 = blockIdx.x * 64, c0 = blockIdx.y * 64, b = blockIdx.z;
  const float* xb = x + (size_t)b * 512 * 4096;
  int t = threadIdx.x;
#pragma unroll
  for (int rep = 0; rep < 16; ++rep) {
    int idx = rep * 256 + t;
    int r = idx >> 6, cc = idx & 63;
    tile[r][cc] = xb[(size_t)(c0 + r) * 4096 + n0 + cc];
  }
  __syncthreads();
  _Float16* xTb = xT + (size_t)b * 4096 * 512;
#pragma unroll
  for (int rep = 0; rep < 16; ++rep) {
    int idx = rep * 256 + t;
    int r = idx >> 6, cc = idx & 63;
    xTb[(size_t)(n0 + r) * 512 + c0 + cc] = (_Float16)tile[cc][r];
  }
}

// ---------------- kernel 2: W_all (640x512) fp16 = [Wq; Wk; Wv] ----------------
__global__ void k_wall(const float* __restrict__ Wq, const float* __restrict__ Wk,
                       const float* __restrict__ Wv, _Float16* __restrict__ W_all) {
  int i = blockIdx.x * 256 + threadIdx.x;
  if (i >= 640 * 512) return;
  int m = i >> 9, c = i & 511;
  float v;
  if (m < 64) v = Wq[m * 512 + c];
  else if (m < 128) v = Wk[(m - 64) * 512 + c];
  else v = Wv[(m - 128) * 512 + c];
  W_all[i] = (_Float16)v;
}

// ---------------- kernel 3: proj GEMM ----------------
__global__ __launch_bounds__(256) void k_proj(
    const _Float16* __restrict__ W_all, const _Float16* __restrict__ xT,
    const float* __restrict__ bq, const float* __restrict__ bk,
    const float* __restrict__ gamma, const float* __restrict__ beta,
    const float* __restrict__ mean, const float* __restrict__ var,
    _Float16* __restrict__ q_buf, _Float16* __restrict__ kT_buf,
    _Float16* __restrict__ v_buf) {
  __shared__ __align__(16) _Float16 A_lds[128 * 32];
  __shared__ __align__(16) _Float16 B_lds[128 * 32];
  int nt = blockIdx.x, mt = blockIdx.y, b = blockIdx.z;
  int t = threadIdx.x, w = t >> 6, lane = t & 63;
  int quad = lane >> 4, l16 = lane & 15;
  int moff = (w & 1) * 64, noff = (w >> 1) * 64;

  f32x4 acc[4][4] = {};

  for (int kk = 0; kk < 16; ++kk) {
    int kc = kk * 32;
#pragma unroll
    for (int c = 0; c < 2; ++c) {
      int row = (w * 2 + c) * 16 + (lane >> 2);
      int kseg = (lane & 3) * 8;
      async_copy16(W_all + (size_t)(mt * 128 + row) * 512 + kc + kseg,
                   (char*)A_lds + (w * 2 + c) * 1024 + lane * 16);
      async_copy16(xT + ((size_t)b * 4096 + nt * 128 + row) * 512 + kc + kseg,
                   (char*)B_lds + (w * 2 + c) * 1024 + lane * 16);
    }
    __syncthreads();
    half8 a[4], bb[4];
#pragma unroll
    for (int mi = 0; mi < 4; ++mi)
      a[mi] = *(const half8*)&A_lds[(moff + 16 * mi + l16) * 32 + 8 * quad];
#pragma unroll
    for (int ni = 0; ni < 4; ++ni)
      bb[ni] = *(const half8*)&B_lds[(noff + 16 * ni + l16) * 32 + 8 * quad];
#pragma unroll
    for (int mi = 0; mi < 4; ++mi)
#pragma unroll
      for (int ni = 0; ni < 4; ++ni)
        acc[mi][ni] = __builtin_amdgcn_mfma_f32_16x16x32_f16(a[mi], bb[ni], acc[mi][ni], 0, 0, 0);
    __syncthreads();
  }

  size_t bN = (size_t)b * 4096;
#pragma unroll
  for (int mi = 0; mi < 4; ++mi) {
    int mbase = mt * 128 + moff + 16 * mi + 4 * quad;
#pragma unroll
    for (int ni = 0; ni < 4; ++ni) {
      int n = nt * 128 + noff + 16 * ni + l16;
#pragma unroll
      for (int i = 0; i < 4; ++i) {
        int m = mbase + i;
        float val = acc[mi][ni][i];
        if (m < 64) {
          q_buf[(bN + n) * 64 + m] = (_Float16)(val + bq[m]);
        } else if (m < 128) {
          kT_buf[(bN + n) * 64 + (m - 64)] = (_Float16)(val + bk[m - 64]);
        } else {
          int vv = m - 128;
          float sc = gamma[vv] * rsqrtf(var[vv] + BN_EPS);
          float sh = beta[vv] - mean[vv] * sc;
          float r = val * sc + sh;
          v_buf[((size_t)b * 512 + vv) * 4096 + n] = (_Float16)(r > 0.f ? r : 0.f);
        }
      }
    }
  }
}

// ---------------- kernel 4: flash attention, split-K over m (2 halves) ----------------
// grid 512: bx&7 = batch (XCD affinity), (bx>>3)&31 = n-tile(128), bx>>8 = m-half.
// WG 512 thr / 8 waves; wave w: S strip rows [16w,16w+16), O chunk V-cols [64w,64w+64).
// Writes UNNORMALIZED partial O (half0 -> fp32 d_out, half1 -> fp16 buffer) + per-row (m,l).
__global__ __launch_bounds__(512, 4) void k_flash(
    const _Float16* __restrict__ q_buf, const _Float16* __restrict__ kT_buf,
    const _Float16* __restrict__ v_buf, float* __restrict__ o0_out,
    _Float16* __restrict__ o1_out, float2* __restrict__ lm) {
  __shared__ __align__(16) _Float16 P_lds[2][128 * 72];
  __shared__ __align__(16) _Float16 K_lds[2][64 * 64];
  __shared__ __align__(16) float alpha_lds[2][128];
  int bx = blockIdx.x;
  int b = bx & 7;
  int n0 = ((bx >> 3) & 31) * 128;
  int half = bx >> 8;
  int m_base = half * 2048;
  int t = threadIdx.x, w = t >> 6, lane = t & 63, quad = lane >> 4, l16 = lane & 15;
  const _Float16* qb = q_buf + (size_t)b * 4096 * 64;
  const char* kbb = (const char*)(kT_buf + (size_t)b * 4096 * 64);
  const _Float16* vp = v_buf + (size_t)b * 512 * 4096 + (size_t)(64 * w + l16) * 4096 + 8 * quad;

  int st_r = w * 8 + (lane >> 3);
  int st_c = (lane & 7) ^ (st_r & 7);
  int st_dst = w * 1024 + lane * 16;
  int st_src = st_r * 128 + st_c * 16;

  half8 aq[2];
#pragma unroll
  for (int s = 0; s < 2; ++s)
    aq[s] = *(const half8*)&qb[(size_t)(n0 + 16 * w + l16) * 64 + 32 * s + 8 * quad];

  f32x4 o[8][4] = {};
  float m_st[4], l_st[4];
#pragma unroll
  for (int i = 0; i < 4; ++i) { m_st[i] = -1e30f; l_st[i] = 0.f; }

  // prefetch V(0); stage K(0) into buf 0
  half8 vreg[8];
#pragma unroll
  for (int c2 = 0; c2 < 4; ++c2)
#pragma unroll
    for (int s = 0; s < 2; ++s)
      vreg[2 * c2 + s] = *(const half8*)&vp[c2 * 65536 + m_base + 32 * s];
  async_copy16(kbb + (size_t)m_base * 128 + st_src, (char*)K_lds[0] + st_dst);
  __syncthreads();

#pragma unroll 1
  for (int it = 0; it < 32; ++it) {
    int m0 = m_base + it * 64;
    int mn = (it == 31) ? m_base : m0 + 64;
    _Float16* Pb = P_lds[it & 1];
    float* Ab = alpha_lds[it & 1];
    const _Float16* Kb = K_lds[it & 1];

    async_copy16(kbb + (size_t)mn * 128 + st_src, (char*)K_lds[(it + 1) & 1] + st_dst);

    // ---- S = Q Kt for this wave's 16-row strip ----
    f32x4 sc[4];
#pragma unroll
    for (int ct = 0; ct < 4; ++ct) {
      int row = 16 * ct + l16;
      int sw = (row & 7) * 16;
      half8 k0 = *(const half8*)((const char*)Kb + row * 128 + ((quad * 16) ^ sw));
      half8 k1 = *(const half8*)((const char*)Kb + row * 128 + (((4 + quad) * 16) ^ sw));
      f32x4 sa = {0.f, 0.f, 0.f, 0.f};
      sa = __builtin_amdgcn_mfma_f32_16x16x32_f16(aq[0], k0, sa, 0, 0, 0);
      sa = __builtin_amdgcn_mfma_f32_16x16x32_f16(aq[1], k1, sa, 0, 0, 0);
      sc[ct] = sa;
    }

    // ---- online softmax; per-lane partial l; write P + alpha ----
#pragma unroll
    for (int i = 0; i < 4; ++i) {
      float mxi = fmaxf(fmaxf(sc[0][i], sc[1][i]), fmaxf(sc[2][i], sc[3][i]));
#pragma unroll
      for (int off = 1; off < 16; off <<= 1) mxi = fmaxf(mxi, __shfl_xor(mxi, off));
      float mnew = fmaxf(m_st[i], mxi);
      float alpha_i = __expf(m_st[i] - mnew);
      m_st[i] = mnew;
      float rsum = 0.f;
#pragma unroll
      for (int ct = 0; ct < 4; ++ct) {
        float pv = __expf(sc[ct][i] - mnew);
        Pb[(16 * w + 4 * quad + i) * 72 + 16 * ct + l16] = (_Float16)pv;
        rsum += pv;
      }
      l_st[i] = l_st[i] * alpha_i + rsum;
      if (l16 == 0) Ab[16 * w + 4 * quad + i] = alpha_i;
    }
    __syncthreads();

    // ---- rescale O (skip row-tiles whose alphas are all 1) ----
#pragma unroll
    for (int rt = 0; rt < 8; ++rt) {
      f32x4 ar = *(const f32x4*)&Ab[16 * rt + 4 * quad];
      bool nd = (ar[0] != 1.f) | (ar[1] != 1.f) | (ar[2] != 1.f) | (ar[3] != 1.f);
      if (__any(nd)) {
#pragma unroll
        for (int c2 = 0; c2 < 4; ++c2)
#pragma unroll
          for (int i = 0; i < 4; ++i) o[rt][c2][i] *= ar[i];
      }
    }

    // ---- O += P @ Vt ; reload vreg for next iter ----
#pragma unroll
    for (int rt = 0; rt < 8; ++rt) {
      half8 pa0 = *(const half8*)&Pb[(16 * rt + l16) * 72 + 8 * quad];
      half8 pa1 = *(const half8*)&Pb[(16 * rt + l16) * 72 + 32 + 8 * quad];
#pragma unroll
      for (int c2 = 0; c2 < 4; ++c2) {
        o[rt][c2] = __builtin_amdgcn_mfma_f32_16x16x32_f16(pa0, vreg[2 * c2], o[rt][c2], 0, 0, 0);
        o[rt][c2] = __builtin_amdgcn_mfma_f32_16x16x32_f16(pa1, vreg[2 * c2 + 1], o[rt][c2], 0, 0, 0);
      }
    }
#pragma unroll
    for (int c2 = 0; c2 < 4; ++c2) {
      vreg[2 * c2]     = *(const half8*)&vp[c2 * 65536 + mn];
      vreg[2 * c2 + 1] = *(const half8*)&vp[c2 * 65536 + mn + 32];
    }
  }

  // ---- finalize: reduce per-lane l partials; write (m,l) and unnormalized O ----
#pragma unroll
  for (int i = 0; i < 4; ++i) {
    float s = l_st[i];
#pragma unroll
    for (int off = 1; off < 16; off <<= 1) s += __shfl_xor(s, off);
    if (l16 == 0) {
      int n = n0 + 16 * w + 4 * quad + i;
      lm[((size_t)b * 4096 + n) * 2 + half] = make_float2(m_st[i], s);
    }
  }
  if (half == 0) {
    float* ob = o0_out + (size_t)b * 512 * 4096;
#pragma unroll
    for (int rt = 0; rt < 8; ++rt)
#pragma unroll
      for (int c2 = 0; c2 < 4; ++c2) {
        int vv = 64 * w + 16 * c2 + l16;
        *(f32x4*)(ob + (size_t)vv * 4096 + n0 + 16 * rt + 4 * quad) = o[rt][c2];
      }
  } else {
    _Float16* ob = o1_out + (size_t)b * 512 * 4096;
#pragma unroll
    for (int rt = 0; rt < 8; ++rt)
#pragma unroll
      for (int c2 = 0; c2 < 4; ++c2) {
        int vv = 64 * w + 16 * c2 + l16;
        half4 h;
#pragma unroll
        for (int i = 0; i < 4; ++i) h[i] = (_Float16)o[rt][c2][i];
        *(half4*)(ob + (size_t)vv * 4096 + n0 + 16 * rt + 4 * quad) = h;
      }
  }
}

// ---------------- kernel 5: turn (m,l) pairs into combine coefficients ----------------
// lm[i*2] <- (c0, c1) where out = O0*c0 + O1*c1
__global__ void k_lmprep(float2* __restrict__ lm) {
  int i = blockIdx.x * 256 + threadIdx.x;  // 32768 (b,n) pairs
  float2 a = lm[i * 2], b2 = lm[i * 2 + 1];
  float M = fmaxf(a.x, b2.x);
  float s0 = __expf(a.x - M), s1 = __expf(b2.x - M);
  float inv = 1.f / (a.y * s0 + b2.y * s1);
  lm[i * 2] = make_float2(s0 * inv, s1 * inv);
}

// ---------------- kernel 6: combine halves: out = O0*c0 + O1*c1 (in place on d_out) ----------------
__global__ void k_combine(float* __restrict__ out, const _Float16* __restrict__ o1,
                          const float2* __restrict__ lm) {
  int idx = blockIdx.x * 256 + threadIdx.x;   // 4,194,304 threads, 4 elems each
  int n4 = (idx & 1023) * 4;
  int bv = idx >> 10;                          // b*512 + v
  size_t base = (size_t)bv * 4096 + n4;
  f32x4 O0 = *(const f32x4*)(out + base);
  half4 O1 = *(const half4*)(o1 + base);
  int bn = (bv >> 9) * 4096 + n4;
  f32x4 r;
#pragma unroll
  for (int j = 0; j < 4; ++j) {
    float2 c = lm[(size_t)(bn + j) * 2];
    r[j] = O0[j] * c.x + (float)O1[j] * c.y;
  }
  *(f32x4*)(out + base) = r;
}

// ---------------- launch ----------------
extern "C" void kernel_launch(void* const* d_in, const int* in_sizes, int n_in,
                              void* d_out, int out_size, void* d_ws, size_t ws_size,
                              hipStream_t stream) {
  const float* x     = (const float*)d_in[0];
  const float* Wq    = (const float*)d_in[1];
  const float* bq    = (const float*)d_in[2];
  const float* Wk    = (const float*)d_in[3];
  const float* bk    = (const float*)d_in[4];
  const float* Wv    = (const float*)d_in[5];
  const float* gamma = (const float*)d_in[6];
  const float* beta  = (const float*)d_in[7];
  const float* mean  = (const float*)d_in[8];
  const float* var   = (const float*)d_in[9];
  float* out = (float*)d_out;

  char* ws = (char*)d_ws;
  _Float16* xT     = (_Float16*)(ws);                 // 33,554,432 B (reused as O1 after k_proj)
  _Float16* W_all  = (_Float16*)(ws + 33554432);      //    655,360 B (reused as lm after k_proj)
  _Float16* q_buf  = (_Float16*)(ws + 34209792);      //  4,194,304 B
  _Float16* kT_buf = (_Float16*)(ws + 38404096);      //  4,194,304 B
  _Float16* v_buf  = (_Float16*)(ws + 42598400);      // 33,554,432 B -> total 76,152,832 B
  _Float16* o1     = xT;                              // dead after k_proj
  float2*   lm     = (float2*)W_all;                  // dead after k_proj (512 KB <= 640 KB)

  k_transpose<<<dim3(64, 8, 8), 256, 0, stream>>>(x, xT);
  k_wall<<<dim3(1280), 256, 0, stream>>>(Wq, Wk, Wv, W_all);
  k_proj<<<dim3(32, 5, 8), 256, 0, stream>>>(W_all, xT, bq, bk, gamma, beta, mean, var,
                                             q_buf, kT_buf, v_buf);
  k_flash<<<dim3(512), 512, 0, stream>>>(q_buf, kT_buf, v_buf, out, o1, lm);
  k_lmprep<<<dim3(128), 256, 0, stream>>>(lm);
  k_combine<<<dim3(16384), 256, 0, stream>>>(out, o1, lm);
}

// Round 6
// 430.510 us; speedup vs baseline: 3.7071x; 3.7071x over previous
//
#include <hip/hip_runtime.h>

typedef __attribute__((ext_vector_type(8))) _Float16 half8;
typedef __attribute__((ext_vector_type(4))) float f32x4;

#define BN_EPS 1e-5f
#define LOG2E 1.4426950408889634f

__device__ __forceinline__ void async_copy16(const void* g, void* l) {
  __builtin_amdgcn_global_load_lds((const __attribute__((address_space(1))) void*)g,
                                   (__attribute__((address_space(3))) void*)l,
                                   16, 0, 0);
}

// ---------------- kernel 1: x (B,C,N) fp32 -> xT (B,N,C) fp16 ----------------
__global__ void k_transpose(const float* __restrict__ x, _Float16* __restrict__ xT) {
  __shared__ float tile[64][65];
  int n0 = blockIdx.x * 64, c0 = blockIdx.y * 64, b = blockIdx.z;
  const float* xb = x + (size_t)b * 512 * 4096;
  int t = threadIdx.x;
#pragma unroll
  for (int rep = 0; rep < 16; ++rep) {
    int idx = rep * 256 + t;
    int r = idx >> 6, cc = idx & 63;
    tile[r][cc] = xb[(size_t)(c0 + r) * 4096 + n0 + cc];
  }
  __syncthreads();
  _Float16* xTb = xT + (size_t)b * 4096 * 512;
#pragma unroll
  for (int rep = 0; rep < 16; ++rep) {
    int idx = rep * 256 + t;
    int r = idx >> 6, cc = idx & 63;
    xTb[(size_t)(n0 + r) * 512 + c0 + cc] = (_Float16)tile[cc][r];
  }
}

// ---------------- kernel 2: W_all (640x512) fp16 = [Wq; Wk; Wv] ----------------
__global__ void k_wall(const float* __restrict__ Wq, const float* __restrict__ Wk,
                       const float* __restrict__ Wv, _Float16* __restrict__ W_all) {
  int i = blockIdx.x * 256 + threadIdx.x;
  if (i >= 640 * 512) return;
  int m = i >> 9, c = i & 511;
  float v;
  if (m < 64) v = Wq[m * 512 + c];
  else if (m < 128) v = Wk[(m - 64) * 512 + c];
  else v = Wv[(m - 128) * 512 + c];
  W_all[i] = (_Float16)v;
}

// ---------------- kernel 3: proj GEMM ----------------
// epilogue: q scaled by log2(e) so flash softmax can use native exp2.
__global__ __launch_bounds__(256) void k_proj(
    const _Float16* __restrict__ W_all, const _Float16* __restrict__ xT,
    const float* __restrict__ bq, const float* __restrict__ bk,
    const float* __restrict__ gamma, const float* __restrict__ beta,
    const float* __restrict__ mean, const float* __restrict__ var,
    _Float16* __restrict__ q_buf, _Float16* __restrict__ kT_buf,
    _Float16* __restrict__ v_buf) {
  __shared__ __align__(16) _Float16 A_lds[128 * 32];
  __shared__ __align__(16) _Float16 B_lds[128 * 32];
  int nt = blockIdx.x, mt = blockIdx.y, b = blockIdx.z;
  int t = threadIdx.x, w = t >> 6, lane = t & 63;
  int quad = lane >> 4, l16 = lane & 15;
  int moff = (w & 1) * 64, noff = (w >> 1) * 64;

  f32x4 acc[4][4] = {};

  for (int kk = 0; kk < 16; ++kk) {
    int kc = kk * 32;
#pragma unroll
    for (int c = 0; c < 2; ++c) {
      int row = (w * 2 + c) * 16 + (lane >> 2);
      int kseg = (lane & 3) * 8;
      async_copy16(W_all + (size_t)(mt * 128 + row) * 512 + kc + kseg,
                   (char*)A_lds + (w * 2 + c) * 1024 + lane * 16);
      async_copy16(xT + ((size_t)b * 4096 + nt * 128 + row) * 512 + kc + kseg,
                   (char*)B_lds + (w * 2 + c) * 1024 + lane * 16);
    }
    __syncthreads();
    half8 a[4], bb[4];
#pragma unroll
    for (int mi = 0; mi < 4; ++mi)
      a[mi] = *(const half8*)&A_lds[(moff + 16 * mi + l16) * 32 + 8 * quad];
#pragma unroll
    for (int ni = 0; ni < 4; ++ni)
      bb[ni] = *(const half8*)&B_lds[(noff + 16 * ni + l16) * 32 + 8 * quad];
#pragma unroll
    for (int mi = 0; mi < 4; ++mi)
#pragma unroll
      for (int ni = 0; ni < 4; ++ni)
        acc[mi][ni] = __builtin_amdgcn_mfma_f32_16x16x32_f16(a[mi], bb[ni], acc[mi][ni], 0, 0, 0);
    __syncthreads();
  }

  size_t bN = (size_t)b * 4096;
#pragma unroll
  for (int mi = 0; mi < 4; ++mi) {
    int mbase = mt * 128 + moff + 16 * mi + 4 * quad;
#pragma unroll
    for (int ni = 0; ni < 4; ++ni) {
      int n = nt * 128 + noff + 16 * ni + l16;
#pragma unroll
      for (int i = 0; i < 4; ++i) {
        int m = mbase + i;
        float val = acc[mi][ni][i];
        if (m < 64) {
          q_buf[(bN + n) * 64 + m] = (_Float16)((val + bq[m]) * LOG2E);
        } else if (m < 128) {
          kT_buf[(bN + n) * 64 + (m - 64)] = (_Float16)(val + bk[m - 64]);
        } else {
          int vv = m - 128;
          float sc = gamma[vv] * rsqrtf(var[vv] + BN_EPS);
          float sh = beta[vv] - mean[vv] * sc;
          float r = val * sc + sh;
          v_buf[((size_t)b * 512 + vv) * 4096 + n] = (_Float16)(r > 0.f ? r : 0.f);
        }
      }
    }
  }
}

// ---------------- kernel 4: flash attention, software-pipelined ----------------
// 512 thr / 8 waves; WG: batch = bx&7 (XCD affinity), 128 Q rows.
// wave w: S strip rows [16w,16w+16), O chunk V-cols [64w,64w+64).
// Pipeline: in barrier interval t, do rescale(t) + PV(t) AND QK(t+1)+softmax(t+1).
// One barrier/iter; P/alpha/K double-buffered; V prefetched in registers.
__global__ __launch_bounds__(512, 2) void k_flash(
    const _Float16* __restrict__ q_buf, const _Float16* __restrict__ kT_buf,
    const _Float16* __restrict__ v_buf, float* __restrict__ out) {
  __shared__ __align__(16) _Float16 P_lds[2][128 * 72];
  __shared__ __align__(16) _Float16 K_lds[2][64 * 64];
  __shared__ __align__(16) float alpha_lds[2][128];
  __shared__ __align__(16) float l_lds[128];
  int bx = blockIdx.x;
  int b = bx & 7;
  int n0 = (bx >> 3) * 128;
  int t = threadIdx.x, w = t >> 6, lane = t & 63, quad = lane >> 4, l16 = lane & 15;
  const _Float16* qb = q_buf + (size_t)b * 4096 * 64;
  const char* kbb = (const char*)(kT_buf + (size_t)b * 4096 * 64);
  const _Float16* vp = v_buf + (size_t)b * 512 * 4096 + (size_t)(64 * w + l16) * 4096 + 8 * quad;

  int st_r = w * 8 + (lane >> 3);
  int st_c = (lane & 7) ^ (st_r & 7);
  int st_dst = w * 1024 + lane * 16;
  int st_src = st_r * 128 + st_c * 16;

  half8 aq[2];
#pragma unroll
  for (int s = 0; s < 2; ++s)
    aq[s] = *(const half8*)&qb[(size_t)(n0 + 16 * w + l16) * 64 + 32 * s + 8 * quad];

  f32x4 o[8][4] = {};
  float m_st[4], l_st[4];
#pragma unroll
  for (int i = 0; i < 4; ++i) { m_st[i] = -1e30f; l_st[i] = 0.f; }

  // QK(block) from K_lds buffer + online softmax -> P/alpha buffers, update m/l
  auto qk_softmax = [&](const _Float16* Kb, _Float16* Pb, float* Ab) {
    f32x4 sc[4];
#pragma unroll
    for (int ct = 0; ct < 4; ++ct) {
      int row = 16 * ct + l16;
      int sw = (row & 7) * 16;
      half8 k0 = *(const half8*)((const char*)Kb + row * 128 + ((quad * 16) ^ sw));
      half8 k1 = *(const half8*)((const char*)Kb + row * 128 + (((4 + quad) * 16) ^ sw));
      f32x4 sa = {0.f, 0.f, 0.f, 0.f};
      sa = __builtin_amdgcn_mfma_f32_16x16x32_f16(aq[0], k0, sa, 0, 0, 0);
      sa = __builtin_amdgcn_mfma_f32_16x16x32_f16(aq[1], k1, sa, 0, 0, 0);
      sc[ct] = sa;
    }
#pragma unroll
    for (int i = 0; i < 4; ++i) {
      float mxi = fmaxf(fmaxf(sc[0][i], sc[1][i]), fmaxf(sc[2][i], sc[3][i]));
#pragma unroll
      for (int off = 1; off < 16; off <<= 1) mxi = fmaxf(mxi, __shfl_xor(mxi, off));
      float mnew = fmaxf(m_st[i], mxi);
      float alpha_i = exp2f(m_st[i] - mnew);
      m_st[i] = mnew;
      float rsum = 0.f;
#pragma unroll
      for (int ct = 0; ct < 4; ++ct) {
        float pv = exp2f(sc[ct][i] - mnew);
        Pb[(16 * w + 4 * quad + i) * 72 + 16 * ct + l16] = (_Float16)pv;
        rsum += pv;
      }
      l_st[i] = l_st[i] * alpha_i + rsum;
      if (l16 == 0) Ab[16 * w + 4 * quad + i] = alpha_i;
    }
  };

  auto rescale = [&](const float* Ab) {
#pragma unroll
    for (int rt = 0; rt < 8; ++rt) {
      f32x4 ar = *(const f32x4*)&Ab[16 * rt + 4 * quad];
      bool nd = (ar[0] != 1.f) | (ar[1] != 1.f) | (ar[2] != 1.f) | (ar[3] != 1.f);
      if (__any(nd)) {
#pragma unroll
        for (int c2 = 0; c2 < 4; ++c2)
#pragma unroll
          for (int i = 0; i < 4; ++i) o[rt][c2][i] *= ar[i];
      }
    }
  };

  // PV from P buffer + vreg; reload vreg for m-offset mn as each pair is consumed
  half8 vreg[8];
  auto pv_step = [&](const _Float16* Pb, int mn) {
#pragma unroll
    for (int rt = 0; rt < 8; ++rt) {
      half8 pa0 = *(const half8*)&Pb[(16 * rt + l16) * 72 + 8 * quad];
      half8 pa1 = *(const half8*)&Pb[(16 * rt + l16) * 72 + 32 + 8 * quad];
#pragma unroll
      for (int c2 = 0; c2 < 4; ++c2) {
        o[rt][c2] = __builtin_amdgcn_mfma_f32_16x16x32_f16(pa0, vreg[2 * c2], o[rt][c2], 0, 0, 0);
        o[rt][c2] = __builtin_amdgcn_mfma_f32_16x16x32_f16(pa1, vreg[2 * c2 + 1], o[rt][c2], 0, 0, 0);
      }
    }
#pragma unroll
    for (int c2 = 0; c2 < 4; ++c2) {
      vreg[2 * c2]     = *(const half8*)&vp[c2 * 65536 + mn];
      vreg[2 * c2 + 1] = *(const half8*)&vp[c2 * 65536 + mn + 32];
    }
  };

  // ---- prologue: V(0) prefetch; K(0)->buf0, K(1)->buf1; QK(0)+softmax(0) ----
#pragma unroll
  for (int c2 = 0; c2 < 4; ++c2)
#pragma unroll
    for (int s = 0; s < 2; ++s)
      vreg[2 * c2 + s] = *(const half8*)&vp[c2 * 65536 + 32 * s];
  async_copy16(kbb + st_src, (char*)K_lds[0] + st_dst);
  async_copy16(kbb + 64 * 128 + st_src, (char*)K_lds[1] + st_dst);
  __syncthreads();
  qk_softmax(K_lds[0], P_lds[0], alpha_lds[0]);

#pragma unroll 1
  for (int it = 0; it < 63; ++it) {
    int cur = it & 1, nxt = cur ^ 1;
    __syncthreads();  // P(it)/alpha(it) visible; K(it+1) staged; PV(it-1) reads done
    int ms = (it + 2 < 64 ? it + 2 : 63) * 64;
    async_copy16(kbb + (size_t)ms * 128 + st_src, (char*)K_lds[cur] + st_dst);
    rescale(alpha_lds[cur]);
    qk_softmax(K_lds[nxt], P_lds[nxt], alpha_lds[nxt]);   // overlaps with PV below
    pv_step(P_lds[cur], (it + 1) * 64);
  }
  // ---- tail: iteration 63 ----
  __syncthreads();
  rescale(alpha_lds[1]);
  pv_step(P_lds[1], 63 * 64);

  // ---- finalize: reduce per-lane l partials, normalize, write ----
#pragma unroll
  for (int i = 0; i < 4; ++i) {
    float s = l_st[i];
#pragma unroll
    for (int off = 1; off < 16; off <<= 1) s += __shfl_xor(s, off);
    if (l16 == 0) l_lds[16 * w + 4 * quad + i] = s;
  }
  __syncthreads();
  float* ob = out + (size_t)b * 512 * 4096;
#pragma unroll
  for (int rt = 0; rt < 8; ++rt) {
    f32x4 lv = *(const f32x4*)&l_lds[16 * rt + 4 * quad];
    f32x4 inv;
#pragma unroll
    for (int i = 0; i < 4; ++i) inv[i] = 1.0f / lv[i];
#pragma unroll
    for (int c2 = 0; c2 < 4; ++c2) {
      int vv = 64 * w + 16 * c2 + l16;
      f32x4 res = o[rt][c2] * inv;
      *(f32x4*)(ob + (size_t)vv * 4096 + n0 + 16 * rt + 4 * quad) = res;
    }
  }
}

// ---------------- launch ----------------
extern "C" void kernel_launch(void* const* d_in, const int* in_sizes, int n_in,
                              void* d_out, int out_size, void* d_ws, size_t ws_size,
                              hipStream_t stream) {
  const float* x     = (const float*)d_in[0];
  const float* Wq    = (const float*)d_in[1];
  const float* bq    = (const float*)d_in[2];
  const float* Wk    = (const float*)d_in[3];
  const float* bk    = (const float*)d_in[4];
  const float* Wv    = (const float*)d_in[5];
  const float* gamma = (const float*)d_in[6];
  const float* beta  = (const float*)d_in[7];
  const float* mean  = (const float*)d_in[8];
  const float* var   = (const float*)d_in[9];
  float* out = (float*)d_out;

  char* ws = (char*)d_ws;
  _Float16* xT     = (_Float16*)(ws);                 // 33,554,432 B
  _Float16* W_all  = (_Float16*)(ws + 33554432);      //    655,360 B
  _Float16* q_buf  = (_Float16*)(ws + 34209792);      //  4,194,304 B
  _Float16* kT_buf = (_Float16*)(ws + 38404096);      //  4,194,304 B
  _Float16* v_buf  = (_Float16*)(ws + 42598400);      // 33,554,432 B -> total 76,152,832 B

  k_transpose<<<dim3(64, 8, 8), 256, 0, stream>>>(x, xT);
  k_wall<<<dim3(1280), 256, 0, stream>>>(Wq, Wk, Wv, W_all);
  k_proj<<<dim3(32, 5, 8), 256, 0, stream>>>(W_all, xT, bq, bk, gamma, beta, mean, var,
                                             q_buf, kT_buf, v_buf);
  k_flash<<<dim3(256), 512, 0, stream>>>(q_buf, kT_buf, v_buf, out);
}